// Round 6
// baseline (171.897 us; speedup 1.0000x reference)
//
#include <hip/hip_runtime.h>

#define HW_   5776   // 76*76
#define W_    76
#define NC_   80     // classes
#define NA_   3      // anchors
#define NB_   16     // batch
#define NPOS  (NB_ * NA_ * HW_)   // 277248 total positions
#define ROWQ  24     // padded float4 slots per LDS position row (xor swizzle)

__device__ __forceinline__ float sigmoidf_(float x) {
    return 1.0f / (1.0f + __expf(-x));
}
// j is always a compile-time constant under #pragma unroll -> folds to a reg name
__device__ __forceinline__ float getc_(float4 f, int j) {
    return j == 0 ? f.x : j == 1 ? f.y : j == 2 ? f.z : f.w;
}

// One wave per block. Lane-pair (lane, lane^32) owns 4 consecutive positions,
// loaded as float4 (1 KB per load instruction -> 4x bytes per vmem request
// slot vs dword loads, attacking the measured per-instruction MLP cap).
// half 0 handles classes 0..39, half 1 classes 40..79; softmax joined via
// __shfl_xor(.,32). Conf output drains through the per-wave LDS transpose
// (program-order DS pipe, no barriers). 180-reg payload: launch_bounds(64,1)
// grants the full 512-VGPR budget so nothing spills.
__global__ __launch_bounds__(64, 1) void yolo_kernel(const float* __restrict__ in,
                                                     float* __restrict__ out) {
    __shared__ float4 buf[32 * ROWQ];   // 12 KB

    const int lane = threadIdx.x;       // 0..63
    const int half = lane >> 5;         // class-half
    const int q    = lane & 31;         // pair index

    const int waveP0 = blockIdx.x * 128;     // wave covers 128 positions
    const int P0     = waveP0 + q * 4;       // this thread: P0 .. P0+3

    const int slab = P0 / HW_;          // b*3+a; P0%4==0, HW_%4==0 -> same slab for all 4
    const int p    = P0 - slab * HW_;   // %4 == 0
    const int a    = slab % NA_;

    const float aw3[3] = {1.5f, 2.375f, 5.0f};   // [12,19,40]/8
    const float ah3[3] = {2.0f, 4.5f, 3.5f};     // [16,36,28]/8
    const float invW = 1.0f / 76.0f;

    const float4* src4 = (const float4*)(in + (size_t)slab * (85 * (size_t)HW_) + p);
    const int chs = HW_ / 4;            // float4 stride per channel = 1444

    // box channels (same addresses in both halves -> merged by coalescer)
    const float4 b0 = src4[0 * chs];
    const float4 b1 = src4[1 * chs];
    const float4 b2 = src4[2 * chs];
    const float4 b3 = src4[3 * chs];
    const float4 b4 = src4[4 * chs];

    // this half's 40 class channels x 4 positions
    const float4* csrc = src4 + (5 + half * 40) * chs;
    float4 v[40];
#pragma unroll
    for (int c = 0; c < 40; ++c) v[c] = csrc[c * chs];

    // softmax over 80 classes (split 40/40 across lane pair), 4 positions at once
    float4 m = v[0];
#pragma unroll
    for (int c = 1; c < 40; ++c) {
        m.x = fmaxf(m.x, v[c].x); m.y = fmaxf(m.y, v[c].y);
        m.z = fmaxf(m.z, v[c].z); m.w = fmaxf(m.w, v[c].w);
    }
    m.x = fmaxf(m.x, __shfl_xor(m.x, 32));
    m.y = fmaxf(m.y, __shfl_xor(m.y, 32));
    m.z = fmaxf(m.z, __shfl_xor(m.z, 32));
    m.w = fmaxf(m.w, __shfl_xor(m.w, 32));
    float4 s = make_float4(0.f, 0.f, 0.f, 0.f);
#pragma unroll
    for (int c = 0; c < 40; ++c) {
        v[c].x = __expf(v[c].x - m.x); s.x += v[c].x;
        v[c].y = __expf(v[c].y - m.y); s.y += v[c].y;
        v[c].z = __expf(v[c].z - m.z); s.z += v[c].z;
        v[c].w = __expf(v[c].w - m.w); s.w += v[c].w;
    }
    s.x += __shfl_xor(s.x, 32);
    s.y += __shfl_xor(s.y, 32);
    s.z += __shfl_xor(s.z, 32);
    s.w += __shfl_xor(s.w, 32);

    const float4 scale = make_float4(sigmoidf_(b4.x) / s.x, sigmoidf_(b4.y) / s.y,
                                     sigmoidf_(b4.z) / s.z, sigmoidf_(b4.w) / s.w);

    // ---- boxes: [B][A*HW][4]; half0 writes j=0,1; half1 writes j=2,3 ----
    // (adjacent instructions hit the same 64B lines -> merged in L2)
    const int x0 = p % W_;              // 76%4==0, p%4==0 -> x0+3 <= 75, no row wrap
    const int y  = p / W_;
    float4* out4 = (float4*)out;
#pragma unroll
    for (int jj = 0; jj < 2; ++jj) {
        const int j = half * 2 + jj;
        const float bx = (sigmoidf_(getc_(b0, j)) + (float)(x0 + j)) * invW;
        const float by = (sigmoidf_(getc_(b1, j)) + (float)y) * invW;
        const float bw = __expf(getc_(b2, j)) * (aw3[a] * invW);
        const float bh = __expf(getc_(b3, j)) * (ah3[a] * invW);
        out4[P0 + j] = make_float4(bx, by, bw, bh);
    }

    // ---- conf via 4-pass per-wave LDS transpose (32 positions per pass) ----
    float4* conf4 = (float4*)out + NPOS + (size_t)waveP0 * 20;
    const int myt = q >> 3;             // pass in which this thread stages
#pragma unroll
    for (int t = 0; t < 4; ++t) {
        if (myt == t) {
            const int lpb = (q & 7) * 4;
#pragma unroll
            for (int j = 0; j < 4; ++j) {
                const int lp = lpb + j;            // local position 0..31
                const float sc = getc_(scale, j);
#pragma unroll
                for (int i = 0; i < 10; ++i) {
                    const int k    = half * 10 + i;
                    const int slot = lp * ROWQ + (k ^ (lp & 7));
                    buf[slot] = make_float4(getc_(v[4*i],   j) * sc,
                                            getc_(v[4*i+1], j) * sc,
                                            getc_(v[4*i+2], j) * sc,
                                            getc_(v[4*i+3], j) * sc);
                }
            }
        }
        // drain 32 positions = 640 float4, fully coalesced (1 KB/instr)
#pragma unroll
        for (int i = 0; i < 10; ++i) {
            const int f    = i * 64 + lane;        // 0..639
            const int lp   = f / 20;
            const int kq   = f - lp * 20;
            const int slot = lp * ROWQ + (kq ^ (lp & 7));
            conf4[t * 640 + f] = buf[slot];
        }
    }
}

extern "C" void kernel_launch(void* const* d_in, const int* in_sizes, int n_in,
                              void* d_out, int out_size, void* d_ws, size_t ws_size,
                              hipStream_t stream) {
    const float* in = (const float*)d_in[0];
    float* out = (float*)d_out;
    const int nblocks = NPOS / 128;   // 2166, exact (128 positions per wave-block)
    yolo_kernel<<<nblocks, 64, 0, stream>>>(in, out);
}